// Round 1
// baseline (101.503 us; speedup 1.0000x reference)
//
#include <hip/hip_runtime.h>

#define NPATCH 16384
#define NDB    16384
#define WS9    9
#define KP     16               // K padded 9 -> 16 for 32x32x16 MFMA
#define JCH    32               // db chunks (grid.y)
#define CHUNK  (NDB / JCH)      // 512 rows per chunk
#define TILES  (CHUNK / 32)     // 16 j-tiles per chunk
// Split-bf16 cosmax error vs numpy fp32 path <= ~6e-6 (lo*lo 3.8e-6 + accum
// 5e-7 + normalize 2e-7 + numpy's own ~1e-6). Band +-2e-5 keeps 3x margin;
// band population ~= 80 patches -> phase2 recheck is cheap.
#define BAND_LO 0.89998f
#define BAND_HI 0.90002f
#define PREP_BLOCKS 144         // 36864 threads: 32768 prep rows + 36864 float4 copy

typedef short bf16x8 __attribute__((ext_vector_type(8)));
typedef float f32x16 __attribute__((ext_vector_type(16)));

#define MAX3(a,b,c) fmaxf(fmaxf((a),(b)),(c))

// numpy-order norm of 9 elements: sqrt(pairwise-8 + remainder), no contraction.
__device__ __forceinline__ float np_norm9(const float* v) {
#pragma clang fp contract(off)
    float q0 = v[0] * v[0], q1 = v[1] * v[1], q2 = v[2] * v[2], q3 = v[3] * v[3];
    float q4 = v[4] * v[4], q5 = v[5] * v[5], q6 = v[6] * v[6], q7 = v[7] * v[7];
    float q8 = v[8] * v[8];
    float s = ((q0 + q1) + (q2 + q3)) + ((q4 + q5) + (q6 + q7));
    s = s + q8;
    return sqrtf(s);
}

// fp32 -> bf16 RTNE (no NaN inputs here), and back
__device__ __forceinline__ unsigned short f2bf(float x) {
    unsigned u = __float_as_uint(x);
    return (unsigned short)((u + 0x7fffu + ((u >> 16) & 1u)) >> 16);
}
__device__ __forceinline__ float bf2f(unsigned short h) {
    return __uint_as_float(((unsigned)h) << 16);
}

// load row of 9, normalize, split to bf16 hi/lo, K-pad to 16, pack 2x int4 per
// array. Bit-identical to the previous in-block staging (proven absmax=0).
__device__ __forceinline__ void stage_row(const float* __restrict__ src,
                                          unsigned short* dh, unsigned short* dl) {
    float v[WS9];
#pragma unroll
    for (int k = 0; k < WS9; k++) v[k] = src[k];
    float inv = 1.0f / np_norm9(v);
    unsigned short h[KP], l[KP];
#pragma unroll
    for (int k = 0; k < KP; k++) {
        float x = (k < WS9) ? v[k] * inv : 0.0f;
        h[k] = f2bf(x);
        l[k] = f2bf(x - bf2f(h[k]));
    }
    int hw[8], lw[8];
#pragma unroll
    for (int k = 0; k < 8; k++) {
        hw[k] = (int)h[2 * k] | ((int)h[2 * k + 1] << 16);
        lw[k] = (int)l[2 * k] | ((int)l[2 * k + 1] << 16);
    }
    ((int4*)dh)[0] = make_int4(hw[0], hw[1], hw[2], hw[3]);
    ((int4*)dh)[1] = make_int4(hw[4], hw[5], hw[6], hw[7]);
    ((int4*)dl)[0] = make_int4(lw[0], lw[1], lw[2], lw[3]);
    ((int4*)dl)[1] = make_int4(lw[4], lw[5], lw[6], lw[7]);
}

// K0: one-shot prep. Normalize+split every patch/db row ONCE into global ws
// (previously re-done 32x/64x per phase1 block = 1.57M stage_rows -> 32K).
// Also does the db->out copy (moved here from the old k_finish) and inits
// band_count.
__global__ __launch_bounds__(256) void k_prep(const float* __restrict__ patches,
                                              const float* __restrict__ db,
                                              unsigned short* __restrict__ pnh,
                                              unsigned short* __restrict__ pnl,
                                              unsigned short* __restrict__ dnh,
                                              unsigned short* __restrict__ dnl,
                                              float* __restrict__ out,
                                              int* __restrict__ band_count) {
    int t = blockIdx.x * 256 + threadIdx.x;       // [0, 36864)
    if (t == 0) *band_count = 0;
    // db -> out rows [0, NDB): 147456 floats = 36864 float4
    ((float4*)out)[t] = ((const float4*)db)[t];
    if (t < NPATCH) {
        stage_row(patches + (size_t)t * WS9, &pnh[(size_t)t * KP], &pnl[(size_t)t * KP]);
    } else if (t < 2 * NPATCH) {
        int r = t - NPATCH;
        stage_row(db + (size_t)r * WS9, &dnh[(size_t)r * KP], &dnl[(size_t)r * KP]);
    }
}

// K1: phase1, now pure MFMA+max. Block = 256 patches (x) x 512-row db chunk
// (y). db chunk hi/lo -> LDS via int4 copies (128B/thread, no split math);
// patch b-frags straight to registers from prepped global (L2-resident).
// LDS 48KB -> 32KB (3 -> 5 blocks/CU). dot = hi*hi + hi*lo + lo*hi via
// 32x32x16 bf16 MFMA (identical sequence -> identical cosmax bits).
__global__ __launch_bounds__(256) void k_phase1(const unsigned short* __restrict__ pnh,
                                                const unsigned short* __restrict__ pnl,
                                                const unsigned short* __restrict__ dnh,
                                                const unsigned short* __restrict__ dnl,
                                                float* __restrict__ partial) {
    __shared__ __align__(16) unsigned short s_dh[CHUNK * KP];
    __shared__ __align__(16) unsigned short s_dl[CHUNK * KP];

    int jbase = blockIdx.y * CHUNK;
    int ibase = blockIdx.x * 256;

    {   // stage db chunk: 512 rows x 32B per array = 16KB each
        const int4* gh = (const int4*)(dnh + (size_t)jbase * KP);
        const int4* gl = (const int4*)(dnl + (size_t)jbase * KP);
        int4* sh = (int4*)s_dh;
        int4* sl = (int4*)s_dl;
#pragma unroll
        for (int u = 0; u < 4; u++) {
            int e = u * 256 + threadIdx.x;        // 1024 int4 per array
            sh[e] = gh[e];
            sl[e] = gl[e];
        }
    }

    int lane = threadIdx.x & 63;
    int wave = threadIdx.x >> 6;
    int col = lane & 31;
    int half = lane >> 5;
    int i0 = ibase + wave * 64;

    const bf16x8* Ph = (const bf16x8*)pnh;        // 2 frags per 16-elem row
    const bf16x8* Pl = (const bf16x8*)pnl;
    bf16x8 b_hi0 = Ph[(size_t)(i0 + col) * 2 + half];
    bf16x8 b_lo0 = Pl[(size_t)(i0 + col) * 2 + half];
    bf16x8 b_hi1 = Ph[(size_t)(i0 + 32 + col) * 2 + half];
    bf16x8 b_lo1 = Pl[(size_t)(i0 + 32 + col) * 2 + half];

    __syncthreads();

    const bf16x8* Ah = (const bf16x8*)s_dh;
    const bf16x8* Al = (const bf16x8*)s_dl;

    f32x16 zc = {0.f,0.f,0.f,0.f,0.f,0.f,0.f,0.f,0.f,0.f,0.f,0.f,0.f,0.f,0.f,0.f};
    float rm0 = -3.0e38f, rm1 = -3.0e38f;

#pragma unroll 2
    for (int t = 0; t < TILES; ++t) {
        bf16x8 a_h = Ah[(t * 32 + col) * 2 + half];
        bf16x8 a_l = Al[(t * 32 + col) * 2 + half];
        f32x16 acc0 = __builtin_amdgcn_mfma_f32_32x32x16_bf16(a_h, b_hi0, zc, 0, 0, 0);
        acc0 = __builtin_amdgcn_mfma_f32_32x32x16_bf16(a_h, b_lo0, acc0, 0, 0, 0);
        acc0 = __builtin_amdgcn_mfma_f32_32x32x16_bf16(a_l, b_hi0, acc0, 0, 0, 0);
        f32x16 acc1 = __builtin_amdgcn_mfma_f32_32x32x16_bf16(a_h, b_hi1, zc, 0, 0, 0);
        acc1 = __builtin_amdgcn_mfma_f32_32x32x16_bf16(a_h, b_lo1, acc1, 0, 0, 0);
        acc1 = __builtin_amdgcn_mfma_f32_32x32x16_bf16(a_l, b_hi1, acc1, 0, 0, 0);
        // max3-fusable tree, depth 3 (was a 32-deep serial fmax chain)
        {
            float u0 = MAX3(acc0[0],  acc0[1],  acc0[2]);
            float u1 = MAX3(acc0[3],  acc0[4],  acc0[5]);
            float u2 = MAX3(acc0[6],  acc0[7],  acc0[8]);
            float u3 = MAX3(acc0[9],  acc0[10], acc0[11]);
            float u4 = MAX3(acc0[12], acc0[13], acc0[14]);
            float u5 = MAX3(u0, u1, acc0[15]);
            float u6 = MAX3(u2, u3, u4);
            rm0 = MAX3(u5, u6, rm0);
        }
        {
            float u0 = MAX3(acc1[0],  acc1[1],  acc1[2]);
            float u1 = MAX3(acc1[3],  acc1[4],  acc1[5]);
            float u2 = MAX3(acc1[6],  acc1[7],  acc1[8]);
            float u3 = MAX3(acc1[9],  acc1[10], acc1[11]);
            float u4 = MAX3(acc1[12], acc1[13], acc1[14]);
            float u5 = MAX3(u0, u1, acc1[15]);
            float u6 = MAX3(u2, u3, u4);
            rm1 = MAX3(u5, u6, rm1);
        }
    }
    rm0 = fmaxf(rm0, __shfl_xor(rm0, 32, 64));
    rm1 = fmaxf(rm1, __shfl_xor(rm1, 32, 64));
    int ti = half ? (i0 + 32 + col) : (i0 + col);
    partial[(size_t)blockIdx.y * NPATCH + ti] = half ? rm1 : rm0;
}

// K2: classify only (copy moved to k_prep): max over 32 chunk-partials,
// definite rows written, band -> global list.
__global__ __launch_bounds__(256) void k_classify(const float* __restrict__ patches,
                                                  const float* __restrict__ partial,
                                                  float* __restrict__ out,
                                                  int* __restrict__ band_list,
                                                  int* __restrict__ band_count) {
    int i = blockIdx.x * 256 + threadIdx.x;
    float cosmax = partial[i];
#pragma unroll
    for (int c = 1; c < JCH; c++)
        cosmax = fmaxf(cosmax, partial[(size_t)c * NPATCH + i]);
    if (cosmax >= BAND_LO && cosmax < BAND_HI) {
        int idx = atomicAdd(band_count, 1);
        band_list[idx] = i;
        return;  // row written by phase 2
    }
    int hit = (cosmax >= BAND_HI) ? 1 : 0;
#pragma unroll
    for (int k = 0; k < WS9; k++)
        out[(size_t)(NDB + i) * WS9 + k] = hit ? 0.0f : patches[(size_t)i * WS9 + k];
}

// K3: exact numpy-mirror recheck for band patches (proven absmax=0).
// 256 blocks grid-stride over ~80 entries -> <=1 entry per block typically.
__global__ __launch_bounds__(256) void k_phase2(const float* __restrict__ patches,
                                                const float* __restrict__ db,
                                                const int* __restrict__ band_list,
                                                const int* __restrict__ band_count,
                                                float* __restrict__ out) {
    __shared__ float sp[WS9];
    __shared__ float snp;
    __shared__ int shit;
    int nb = *band_count;
    for (int idx = blockIdx.x; idx < nb; idx += gridDim.x) {
        int i = band_list[idx];
        if (threadIdx.x == 0) {
            float p[WS9];
            for (int k = 0; k < WS9; k++) { p[k] = patches[(size_t)i * WS9 + k]; sp[k] = p[k]; }
            snp = np_norm9(p);
            shit = 0;
        }
        __syncthreads();
        float p[WS9];
#pragma unroll
        for (int k = 0; k < WS9; k++) p[k] = sp[k];
        float npn = snp;
        int hit = 0;
        for (int j = (int)threadIdx.x; j < NDB; j += 256) {
            float d[WS9];
#pragma unroll
            for (int k = 0; k < WS9; k++) d[k] = db[(size_t)j * WS9 + k];
            float dot = 0.0f;
#pragma unroll
            for (int k = 0; k < WS9; k++) dot = fmaf(p[k], d[k], dot);
            float nd = np_norm9(d);
            float cs = dot / (npn * nd);          // IEEE fp32 divide
            if (!((double)cs < 0.9)) hit = 1;     // numpy promotes to f64
        }
        if (hit) atomicOr(&shit, 1);
        __syncthreads();
        int m = shit;
        if (threadIdx.x < WS9)
            out[(size_t)(NDB + i) * WS9 + threadIdx.x] = m ? 0.0f : sp[threadIdx.x];
        __syncthreads();
    }
}

extern "C" void kernel_launch(void* const* d_in, const int* in_sizes, int n_in,
                              void* d_out, int out_size, void* d_ws, size_t ws_size,
                              hipStream_t stream) {
    const float* patches = (const float*)d_in[0];  // [16384][9]
    const float* db      = (const float*)d_in[1];  // [16384][9]
    float* out = (float*)d_out;                    // [32768][9]

    // ws layout: partial (JCH*NPATCH f32 = 2MB) | band_list (64KB) |
    //            band_count (pad to 256B) | pnh | pnl | dnh | dnl (512KB each)
    char* wsb = (char*)d_ws;
    size_t o_partial = 0;
    size_t o_blist   = (size_t)JCH * NPATCH * 4;                 // 2 MB
    size_t o_bcount  = o_blist + (size_t)NPATCH * 4;             // +64 KB
    size_t o_pnh     = o_bcount + 256;
    size_t o_pnl     = o_pnh + (size_t)NPATCH * KP * 2;          // 512 KB each
    size_t o_dnh     = o_pnl + (size_t)NPATCH * KP * 2;
    size_t o_dnl     = o_dnh + (size_t)NDB * KP * 2;

    float* partial          = (float*)(wsb + o_partial);
    int*   band_list        = (int*)(wsb + o_blist);
    int*   band_count       = (int*)(wsb + o_bcount);
    unsigned short* pnh     = (unsigned short*)(wsb + o_pnh);
    unsigned short* pnl     = (unsigned short*)(wsb + o_pnl);
    unsigned short* dnh     = (unsigned short*)(wsb + o_dnh);
    unsigned short* dnl     = (unsigned short*)(wsb + o_dnl);

    k_prep<<<dim3(PREP_BLOCKS), dim3(256), 0, stream>>>(patches, db, pnh, pnl,
                                                        dnh, dnl, out, band_count);
    k_phase1<<<dim3(NPATCH / 256, JCH), dim3(256), 0, stream>>>(pnh, pnl, dnh, dnl,
                                                                partial);
    k_classify<<<dim3(NPATCH / 256), dim3(256), 0, stream>>>(patches, partial, out,
                                                             band_list, band_count);
    k_phase2<<<dim3(256), dim3(256), 0, stream>>>(patches, db, band_list, band_count, out);
}